// Round 7
// baseline (333.538 us; speedup 1.0000x reference)
//
#include <hip/hip_runtime.h>

#define NGRAPH 4096
#define NNODE  64
#define NDIM   128
#define NFP    2048
#define NLAYER 3
#define PH 136   // sh pitch (bf16): 68 dwords === 4 mod 32 -> bank-uniform b128 row reads
#define PA 72    // sadj pitch: 36 dwords === 4 mod 32 (proven R8 family)

typedef __attribute__((ext_vector_type(8))) short short8;
typedef __attribute__((ext_vector_type(4))) float f32x4;
typedef __bf16 bf16x2 __attribute__((ext_vector_type(2)));

union S8 { short8 s8; unsigned d[4]; };

static __device__ inline ushort f2bf(float f) {  // RNE fp32 -> bf16 (fallback path)
  unsigned u = __float_as_uint(f);
  u += 0x7FFF + ((u >> 16) & 1);
  return (ushort)(u >> 16);
}

// packed fp32x2 -> bf16x2 in one HW instr on gfx950 (v_cvt_pk_bf16_f32)
static __device__ inline unsigned pkbf(float x, float y) {
#if __has_builtin(__builtin_amdgcn_cvt_pk_bf16_f32)
  bf16x2 v = __builtin_amdgcn_cvt_pk_bf16_f32(x, y);
  return __builtin_bit_cast(unsigned, v);
#else
  return (unsigned)f2bf(x) | ((unsigned)f2bf(y) << 16);
#endif
}

// W in bf16, native [l][k_out][d] layout (B-frag reads W rows directly).
__device__ __align__(16) ushort g_wbf[NLAYER * NDIM * NDIM];
// emb in bf16: gather in the hot kernel becomes a pure b128 copy.
__device__ __align__(16) ushort g_ebf[NFP * NDIM];   // 512 KB

__global__ __launch_bounds__(256) void convert_w(const float* __restrict__ W) {
  int i = blockIdx.x * 256 + threadIdx.x;   // 192 blocks, exact
  g_wbf[i] = f2bf(W[i]);
}

__global__ __launch_bounds__(256) void convert_emb(const float* __restrict__ emb) {
  int i = blockIdx.x * 256 + threadIdx.x;   // 1024 blocks, exact
  g_ebf[i] = f2bf(emb[i]);
}

// R15 = R13 (best: 80.3us) + residency attack.  R14 post-mortem: any LDS-size
// increase that drops blocks/CU loses; no pipe >45% -> stall/overlap-bound.
//  (1) single sh buffer (no ping-pong) + small sadj staging buffer: LDS
//      26.6 KB -> 6 blocks/CU (vs 3).  Cost: 2nd barrier per layer (in-place
//      h overwrite), skipped on the last layer; cheap at high residency.
//  (2) emb pre-converted to bf16 (g_ebf): gather = straight b128 copy; kills
//      16 pkbf/thread + the fp32 dependency chain in the prologue.
//  Transpose stays R13's verified bpermute (R14's zt cost occupancy).
//  W dedup preserved (R11 lesson: W redundancy = ~45us of hidden L2 time).
//  (256,6): 85-VGPR cap, comfortably above the ~60 live set (R10 lesson).
__global__ __launch_bounds__(256, 6) void mpnn_mfma(
    const int* __restrict__ fps, const float* __restrict__ adj,
    const float* __restrict__ emb, const float* __restrict__ bias,
    float* __restrict__ out) {
  __shared__ __align__(16) ushort sh[NNODE * PH];     // h (in-place)  17408 B
  __shared__ __align__(16) ushort sadj[NNODE * PA];   // adj stage      9216 B

  const int g    = blockIdx.x;
  const int t    = threadIdx.x;
  const int w    = t >> 6;        // wave 0..3
  const int lane = t & 63;
  const int r    = lane & 15;     // MFMA row/col index
  const int q    = lane >> 4;     // quad 0..3
  const int n0   = w << 5;        // wave's 32-wide kout region (m1) == d region (m2)

  // bpermute addresses for the z C-frag -> A-frag quad permute (R8-verified mapping)
  const int addr0 = (r + 32 * (q & 1)) << 2;   // p = 0,1
  const int addr1 = addr0 + 64;                // p = 2,3
  const bool hiQ  = (q >= 2);                  // source register select (node>=16 within 32)

  // ---- gather h0 = bf16 emb rows -> sh (pure b128 copy, no conversion) ----
  const int* fg = fps + g * NNODE;
#pragma unroll
  for (int it = 0; it < 4; ++it) {
    int idx = it * 256 + t;               // 1024 b128s
    int n = idx >> 4;
    int c = (idx & 15) << 3;
    short8 v = *(const short8*)(g_ebf + fg[n] * NDIM + c);
    *(short8*)(sh + n * PH + c) = v;
  }

  // ---- adjacency -> sadj: bf16(I + A), staged once, cooperatively coalesced ----
  const float* adjg = adj + (size_t)g * NNODE * NNODE;
#pragma unroll
  for (int it = 0; it < 4; ++it) {
    int idx = it * 256 + t;               // 1024 float4s
    int n = idx >> 4;
    int c = (idx & 15) << 2;
    float4 v = *(const float4*)(adjg + n * NNODE + c);
    v.x += (n == c + 0) ? 1.0f : 0.0f;    // fold residual: I + A
    v.y += (n == c + 1) ? 1.0f : 0.0f;
    v.z += (n == c + 2) ? 1.0f : 0.0f;
    v.w += (n == c + 3) ? 1.0f : 0.0f;
    uint2 u = {pkbf(v.x, v.y), pkbf(v.z, v.w)};
    *(uint2*)(sadj + n * PA + c) = u;
  }

  // ---- bias for all layers, both slabs -> registers ----
  float bv[NLAYER][2];
#pragma unroll
  for (int l = 0; l < NLAYER; ++l) {
    bv[l][0] = bias[l * NDIM + n0 + r];
    bv[l][1] = bias[l * NDIM + n0 + 16 + r];
  }

  __syncthreads();   // staging visible (sh: h0, sadj: I+A)

  // ---- (I+A) B-frags -> registers, once per block (layer-invariant) ----
  // fbr[kh][nt] lane(r,q): (I+A)[node'=nt*16+r][node=kh*32+8q+e]
  // sadj is read-only from here on: no barrier needed after the hoist.
  short8 fbr[2][4];
#pragma unroll
  for (int kh = 0; kh < 2; ++kh)
#pragma unroll
    for (int nt = 0; nt < 4; ++nt)
      fbr[kh][nt] = *(const short8*)(sadj + (nt * 16 + r) * PA + kh * 32 + 8 * q);

#pragma unroll 1   // real loop: avoid cross-layer load hoisting -> spill (R6 lesson)
  for (int l = 0; l < NLAYER; ++l) {
    const ushort* Wl = g_wbf + l * NDIM * NDIM;

    // ---- m1: z[node][n0-region(32)] = relu(h * W^T + b), two 16-slabs ----
    f32x4 acc[2][4];
#pragma unroll
    for (int s = 0; s < 2; ++s)
#pragma unroll
      for (int mt = 0; mt < 4; ++mt)
        acc[s][mt] = (f32x4){bv[l][s], bv[l][s], bv[l][s], bv[l][s]};
#pragma unroll
    for (int k0 = 0; k0 < NDIM; k0 += 32) {
      short8 ah[4];                       // loaded ONCE, feeds both slabs
#pragma unroll
      for (int mt = 0; mt < 4; ++mt)
        ah[mt] = *(const short8*)(sh + (mt * 16 + r) * PH + k0 + 8 * q);
#pragma unroll
      for (int s = 0; s < 2; ++s) {
        short8 bw = *(const short8*)(Wl + (n0 + s * 16 + r) * NDIM + k0 + 8 * q);
#pragma unroll
        for (int mt = 0; mt < 4; ++mt)
          acc[s][mt] = __builtin_amdgcn_mfma_f32_16x16x32_bf16(ah[mt], bw, acc[s][mt], 0, 0, 0);
      }
    }

    // ---- relu -> packed bf16 in registers ----
    unsigned zc[2][4][2];   // [slab][mt: node tile][node pair within quad-rows]
#pragma unroll
    for (int s = 0; s < 2; ++s)
#pragma unroll
      for (int mt = 0; mt < 4; ++mt) {
        f32x4 a = acc[s][mt];
        zc[s][mt][0] = pkbf(fmaxf(a[0], 0.f), fmaxf(a[1], 0.f));
        zc[s][mt][1] = pkbf(fmaxf(a[2], 0.f), fmaxf(a[3], 0.f));
      }

    // ---- m2: houtT[d in n0-region][node'] = zT * (I+A)^T, B-frags from registers ----
    f32x4 acc2[2][4];
#pragma unroll
    for (int s = 0; s < 2; ++s)
#pragma unroll
      for (int nt = 0; nt < 4; ++nt) acc2[s][nt] = (f32x4){0.f, 0.f, 0.f, 0.f};
#pragma unroll
    for (int s = 0; s < 2; ++s) {
#pragma unroll
      for (int kh = 0; kh < 2; ++kh) {
        S8 az;
#pragma unroll
        for (int p = 0; p < 4; ++p) {
          int comp = p & 1;
          int lo = __builtin_amdgcn_ds_bpermute((p < 2) ? addr0 : addr1,
                                                (int)zc[s][2 * kh][comp]);
          int hi = __builtin_amdgcn_ds_bpermute((p < 2) ? addr0 : addr1,
                                                (int)zc[s][2 * kh + 1][comp]);
          az.d[p] = (unsigned)(hiQ ? hi : lo);
        }
#pragma unroll
        for (int nt = 0; nt < 4; ++nt)
          acc2[s][nt] = __builtin_amdgcn_mfma_f32_16x16x32_bf16(az.s8, fbr[kh][nt], acc2[s][nt], 0, 0, 0);
      }
    }

    if (l < NLAYER - 1) {
      __syncthreads();   // #1: ALL waves' m1 reads of sh done -> safe to overwrite
#pragma unroll
      for (int s = 0; s < 2; ++s)
#pragma unroll
        for (int nt = 0; nt < 4; ++nt) {
          f32x4 a = acc2[s][nt];
          uint2 u = {pkbf(a[0], a[1]), pkbf(a[2], a[3])};
          *(uint2*)(sh + (nt * 16 + r) * PH + n0 + s * 16 + 4 * q) = u;
        }
      __syncthreads();   // #2: writes visible before next layer's reads
    } else {
      // ---- sum-pool: out[g][d] = sum_node' h[node'][d] ----
#pragma unroll
      for (int s = 0; s < 2; ++s) {
        f32x4 sum;
#pragma unroll
        for (int i = 0; i < 4; ++i)
          sum[i] = acc2[s][0][i] + acc2[s][1][i] + acc2[s][2][i] + acc2[s][3][i];
#pragma unroll
        for (int m = 1; m <= 8; m <<= 1) {
          sum[0] += __shfl_xor(sum[0], m);
          sum[1] += __shfl_xor(sum[1], m);
          sum[2] += __shfl_xor(sum[2], m);
          sum[3] += __shfl_xor(sum[3], m);
        }
        if (r == 0) {
          float4 o = {sum[0], sum[1], sum[2], sum[3]};
          *(float4*)(out + (size_t)g * NDIM + n0 + s * 16 + 4 * q) = o;
        }
      }
    }
  }
}

extern "C" void kernel_launch(void* const* d_in, const int* in_sizes, int n_in,
                              void* d_out, int out_size, void* d_ws, size_t ws_size,
                              hipStream_t stream) {
  const int*   fps  = (const int*)d_in[0];
  const float* adj  = (const float*)d_in[1];
  const float* emb  = (const float*)d_in[2];
  const float* W    = (const float*)d_in[3];
  const float* bias = (const float*)d_in[4];
  float* out = (float*)d_out;

  hipLaunchKernelGGL(convert_w, dim3(192), dim3(256), 0, stream, W);
  hipLaunchKernelGGL(convert_emb, dim3(1024), dim3(256), 0, stream, emb);
  hipLaunchKernelGGL(mpnn_mfma, dim3(NGRAPH), dim3(256), 0, stream,
                     fps, adj, emb, bias, out);
}

// Round 8
// 160.865 us; speedup vs baseline: 2.0734x; 2.0734x over previous
//
#include <hip/hip_runtime.h>

#define NGRAPH 4096
#define NNODE  64
#define NDIM   128
#define NFP    2048
#define NLAYER 3
#define PH 136   // sh pitch (bf16): 68 dwords === 4 mod 32 -> bank-uniform b128 row reads
#define PA 72    // sadj pitch: 36 dwords === 4 mod 32 (proven R8 family)

typedef __attribute__((ext_vector_type(8))) short short8;
typedef __attribute__((ext_vector_type(4))) float f32x4;
typedef __bf16 bf16x2 __attribute__((ext_vector_type(2)));

union S8 { short8 s8; unsigned d[4]; };

static __device__ inline ushort f2bf(float f) {  // RNE fp32 -> bf16 (fallback path)
  unsigned u = __float_as_uint(f);
  u += 0x7FFF + ((u >> 16) & 1);
  return (ushort)(u >> 16);
}

// packed fp32x2 -> bf16x2 in one HW instr on gfx950 (v_cvt_pk_bf16_f32)
static __device__ inline unsigned pkbf(float x, float y) {
#if __has_builtin(__builtin_amdgcn_cvt_pk_bf16_f32)
  bf16x2 v = __builtin_amdgcn_cvt_pk_bf16_f32(x, y);
  return __builtin_bit_cast(unsigned, v);
#else
  return (unsigned)f2bf(x) | ((unsigned)f2bf(y) << 16);
#endif
}

// W in bf16, native [l][k_out][d] layout (B-frag reads W rows directly).
__device__ __align__(16) ushort g_wbf[NLAYER * NDIM * NDIM];
// emb in bf16: gather in the hot kernel becomes a pure b128 copy.
__device__ __align__(16) ushort g_ebf[NFP * NDIM];   // 512 KB

__global__ __launch_bounds__(256) void convert_w(const float* __restrict__ W) {
  int i = blockIdx.x * 256 + threadIdx.x;   // 192 blocks, exact
  g_wbf[i] = f2bf(W[i]);
}

__global__ __launch_bounds__(256) void convert_emb(const float* __restrict__ emb) {
  int i = blockIdx.x * 256 + threadIdx.x;   // 1024 blocks, exact
  g_ebf[i] = f2bf(emb[i]);
}

// R16 = R15's structure with the spill fixed: (256,6)'s 85-VGPR cap was below
// the ~100-register live set -> compiler chose 40 VGPR and spilled (532MB
// FETCH / 334MB WRITE of scratch, 250us).  Second occurrence of the R10
// failure mode; rule: the launch-bounds VGPR cap must exceed the live set.
// (256,4) = 128-VGPR cap.  R13's identical register set compiled to 56 VGPR
// under this cap; at <=64 VGPR the HW allows 8 waves/SIMD, so residency is
// LDS-limited at 6 blocks/CU (26.6 KB x 6 = 160 KB) -- the occupancy R15
// wanted, without the spill.
//  (1) single sh buffer (no ping-pong) + sadj staging: 26.6 KB LDS.
//      Cost: 2nd barrier per layer (in-place h overwrite), skipped last layer.
//  (2) emb pre-converted to bf16 (g_ebf): gather = straight b128 copy.
//  Transpose = R13's verified bpermute; fbr hoist + W dedup preserved.
__global__ __launch_bounds__(256, 4) void mpnn_mfma(
    const int* __restrict__ fps, const float* __restrict__ adj,
    const float* __restrict__ emb, const float* __restrict__ bias,
    float* __restrict__ out) {
  __shared__ __align__(16) ushort sh[NNODE * PH];     // h (in-place)  17408 B
  __shared__ __align__(16) ushort sadj[NNODE * PA];   // adj stage      9216 B

  const int g    = blockIdx.x;
  const int t    = threadIdx.x;
  const int w    = t >> 6;        // wave 0..3
  const int lane = t & 63;
  const int r    = lane & 15;     // MFMA row/col index
  const int q    = lane >> 4;     // quad 0..3
  const int n0   = w << 5;        // wave's 32-wide kout region (m1) == d region (m2)

  // bpermute addresses for the z C-frag -> A-frag quad permute (R8-verified mapping)
  const int addr0 = (r + 32 * (q & 1)) << 2;   // p = 0,1
  const int addr1 = addr0 + 64;                // p = 2,3
  const bool hiQ  = (q >= 2);                  // source register select (node>=16 within 32)

  // ---- gather h0 = bf16 emb rows -> sh (pure b128 copy, no conversion) ----
  const int* fg = fps + g * NNODE;
#pragma unroll
  for (int it = 0; it < 4; ++it) {
    int idx = it * 256 + t;               // 1024 b128s
    int n = idx >> 4;
    int c = (idx & 15) << 3;
    short8 v = *(const short8*)(g_ebf + fg[n] * NDIM + c);
    *(short8*)(sh + n * PH + c) = v;
  }

  // ---- adjacency -> sadj: bf16(I + A), staged once, cooperatively coalesced ----
  const float* adjg = adj + (size_t)g * NNODE * NNODE;
#pragma unroll
  for (int it = 0; it < 4; ++it) {
    int idx = it * 256 + t;               // 1024 float4s
    int n = idx >> 4;
    int c = (idx & 15) << 2;
    float4 v = *(const float4*)(adjg + n * NNODE + c);
    v.x += (n == c + 0) ? 1.0f : 0.0f;    // fold residual: I + A
    v.y += (n == c + 1) ? 1.0f : 0.0f;
    v.z += (n == c + 2) ? 1.0f : 0.0f;
    v.w += (n == c + 3) ? 1.0f : 0.0f;
    uint2 u = {pkbf(v.x, v.y), pkbf(v.z, v.w)};
    *(uint2*)(sadj + n * PA + c) = u;
  }

  // ---- bias for all layers, both slabs -> registers ----
  float bv[NLAYER][2];
#pragma unroll
  for (int l = 0; l < NLAYER; ++l) {
    bv[l][0] = bias[l * NDIM + n0 + r];
    bv[l][1] = bias[l * NDIM + n0 + 16 + r];
  }

  __syncthreads();   // staging visible (sh: h0, sadj: I+A)

  // ---- (I+A) B-frags -> registers, once per block (layer-invariant) ----
  // fbr[kh][nt] lane(r,q): (I+A)[node'=nt*16+r][node=kh*32+8q+e]
  // sadj is read-only from here on: no barrier needed after the hoist.
  short8 fbr[2][4];
#pragma unroll
  for (int kh = 0; kh < 2; ++kh)
#pragma unroll
    for (int nt = 0; nt < 4; ++nt)
      fbr[kh][nt] = *(const short8*)(sadj + (nt * 16 + r) * PA + kh * 32 + 8 * q);

#pragma unroll 1   // real loop: avoid cross-layer load hoisting -> spill (R6 lesson)
  for (int l = 0; l < NLAYER; ++l) {
    const ushort* Wl = g_wbf + l * NDIM * NDIM;

    // ---- m1: z[node][n0-region(32)] = relu(h * W^T + b), two 16-slabs ----
    f32x4 acc[2][4];
#pragma unroll
    for (int s = 0; s < 2; ++s)
#pragma unroll
      for (int mt = 0; mt < 4; ++mt)
        acc[s][mt] = (f32x4){bv[l][s], bv[l][s], bv[l][s], bv[l][s]};
#pragma unroll
    for (int k0 = 0; k0 < NDIM; k0 += 32) {
      short8 ah[4];                       // loaded ONCE, feeds both slabs
#pragma unroll
      for (int mt = 0; mt < 4; ++mt)
        ah[mt] = *(const short8*)(sh + (mt * 16 + r) * PH + k0 + 8 * q);
#pragma unroll
      for (int s = 0; s < 2; ++s) {
        short8 bw = *(const short8*)(Wl + (n0 + s * 16 + r) * NDIM + k0 + 8 * q);
#pragma unroll
        for (int mt = 0; mt < 4; ++mt)
          acc[s][mt] = __builtin_amdgcn_mfma_f32_16x16x32_bf16(ah[mt], bw, acc[s][mt], 0, 0, 0);
      }
    }

    // ---- relu -> packed bf16 in registers ----
    unsigned zc[2][4][2];   // [slab][mt: node tile][node pair within quad-rows]
#pragma unroll
    for (int s = 0; s < 2; ++s)
#pragma unroll
      for (int mt = 0; mt < 4; ++mt) {
        f32x4 a = acc[s][mt];
        zc[s][mt][0] = pkbf(fmaxf(a[0], 0.f), fmaxf(a[1], 0.f));
        zc[s][mt][1] = pkbf(fmaxf(a[2], 0.f), fmaxf(a[3], 0.f));
      }

    // ---- m2: houtT[d in n0-region][node'] = zT * (I+A)^T, B-frags from registers ----
    f32x4 acc2[2][4];
#pragma unroll
    for (int s = 0; s < 2; ++s)
#pragma unroll
      for (int nt = 0; nt < 4; ++nt) acc2[s][nt] = (f32x4){0.f, 0.f, 0.f, 0.f};
#pragma unroll
    for (int s = 0; s < 2; ++s) {
#pragma unroll
      for (int kh = 0; kh < 2; ++kh) {
        S8 az;
#pragma unroll
        for (int p = 0; p < 4; ++p) {
          int comp = p & 1;
          int lo = __builtin_amdgcn_ds_bpermute((p < 2) ? addr0 : addr1,
                                                (int)zc[s][2 * kh][comp]);
          int hi = __builtin_amdgcn_ds_bpermute((p < 2) ? addr0 : addr1,
                                                (int)zc[s][2 * kh + 1][comp]);
          az.d[p] = (unsigned)(hiQ ? hi : lo);
        }
#pragma unroll
        for (int nt = 0; nt < 4; ++nt)
          acc2[s][nt] = __builtin_amdgcn_mfma_f32_16x16x32_bf16(az.s8, fbr[kh][nt], acc2[s][nt], 0, 0, 0);
      }
    }

    if (l < NLAYER - 1) {
      __syncthreads();   // #1: ALL waves' m1 reads of sh done -> safe to overwrite
#pragma unroll
      for (int s = 0; s < 2; ++s)
#pragma unroll
        for (int nt = 0; nt < 4; ++nt) {
          f32x4 a = acc2[s][nt];
          uint2 u = {pkbf(a[0], a[1]), pkbf(a[2], a[3])};
          *(uint2*)(sh + (nt * 16 + r) * PH + n0 + s * 16 + 4 * q) = u;
        }
      __syncthreads();   // #2: writes visible before next layer's reads
    } else {
      // ---- sum-pool: out[g][d] = sum_node' h[node'][d] ----
#pragma unroll
      for (int s = 0; s < 2; ++s) {
        f32x4 sum;
#pragma unroll
        for (int i = 0; i < 4; ++i)
          sum[i] = acc2[s][0][i] + acc2[s][1][i] + acc2[s][2][i] + acc2[s][3][i];
#pragma unroll
        for (int m = 1; m <= 8; m <<= 1) {
          sum[0] += __shfl_xor(sum[0], m);
          sum[1] += __shfl_xor(sum[1], m);
          sum[2] += __shfl_xor(sum[2], m);
          sum[3] += __shfl_xor(sum[3], m);
        }
        if (r == 0) {
          float4 o = {sum[0], sum[1], sum[2], sum[3]};
          *(float4*)(out + (size_t)g * NDIM + n0 + s * 16 + 4 * q) = o;
        }
      }
    }
  }
}

extern "C" void kernel_launch(void* const* d_in, const int* in_sizes, int n_in,
                              void* d_out, int out_size, void* d_ws, size_t ws_size,
                              hipStream_t stream) {
  const int*   fps  = (const int*)d_in[0];
  const float* adj  = (const float*)d_in[1];
  const float* emb  = (const float*)d_in[2];
  const float* W    = (const float*)d_in[3];
  const float* bias = (const float*)d_in[4];
  float* out = (float*)d_out;

  hipLaunchKernelGGL(convert_w, dim3(192), dim3(256), 0, stream, W);
  hipLaunchKernelGGL(convert_emb, dim3(1024), dim3(256), 0, stream, emb);
  hipLaunchKernelGGL(mpnn_mfma, dim3(NGRAPH), dim3(256), 0, stream,
                     fps, adj, emb, bias, out);
}